// Round 9
// baseline (202.854 us; speedup 1.0000x reference)
//
#include <hip/hip_runtime.h>
#include <stdint.h>

typedef unsigned short u16;
typedef __bf16 v8bf __attribute__((ext_vector_type(8)));
typedef float  v4f  __attribute__((ext_vector_type(4)));

#define NPIX   32768
#define DIM    256
#define KCODE  1024
#define HW     1024

// workspace layout (bytes)
#define WS_EB    0                         // bf16 [KCODE][DIM]  = 512 KB
#define WS_NORM  524288                    // f32  [KCODE]       = 4 KB
#define WS_ACC   (WS_NORM + 4096)          // f32  [1]

// ---------------------------------------------------------------- kernel A
__global__ __launch_bounds__(256) void k_prep(const float* __restrict__ E,
                                              u16* __restrict__ Eb,
                                              float* __restrict__ norms,
                                              float* __restrict__ acc) {
  const int c = blockIdx.x, t = threadIdx.x;
  const float v = E[c * DIM + t];
  const __bf16 h = (__bf16)v;
  Eb[c * DIM + t] = __builtin_bit_cast(unsigned short, h);
  float s = v * v;
  #pragma unroll
  for (int m = 32; m; m >>= 1) s += __shfl_xor(s, m, 64);
  __shared__ float wsum[4];
  if ((t & 63) == 0) wsum[t >> 6] = s;
  __syncthreads();
  if (t == 0) {
    norms[c] = wsum[0] + wsum[1] + wsum[2] + wsum[3];
    if (c == 0) *acc = 0.f;
  }
}

// ---------------------------------------------------------------- fused VQ
// Barrier-free: one wave owns 16 pixels end-to-end. 2048 waves = 512 blocks.
// No LDS staging at all: A direct from HBM (coalesced 64B chunks), B tiles
// register-double-buffered direct from L2 (codebook is 512KB, L2-resident,
// L1 shared by the block's 4 lockstep-ish waves), loss from minv + ||x||^2.

#define MFMA(A, B, C) __builtin_amdgcn_mfma_f32_16x16x32_bf16(A, B, C, 0, 0, 0)

#define ARGMIN_STEP(P, NRM, CODE)                                   \
  {                                                                 \
    v4f aA = {0.f, 0.f, 0.f, 0.f}, aB = {0.f, 0.f, 0.f, 0.f};       \
    aA = MFMA(a[0], P[0], aA);                                      \
    aB = MFMA(a[1], P[1], aB);                                      \
    aA = MFMA(a[2], P[2], aA);                                      \
    aB = MFMA(a[3], P[3], aB);                                      \
    aA = MFMA(a[4], P[4], aA);                                      \
    aB = MFMA(a[5], P[5], aB);                                      \
    aA = MFMA(a[6], P[6], aA);                                      \
    aB = MFMA(a[7], P[7], aB);                                      \
    _Pragma("unroll")                                               \
    for (int i = 0; i < 4; ++i) {                                   \
      const float d = (NRM)-2.f * (aA[i] + aB[i]);                  \
      if (d < minv[i]) { minv[i] = d; mini[i] = (CODE); }           \
    }                                                               \
  }

__global__ __launch_bounds__(256) void k_vq(const float* __restrict__ latents,
                                            const u16* __restrict__ Eb,
                                            const float* __restrict__ E,
                                            const float* __restrict__ norms,
                                            float* __restrict__ out,
                                            float* __restrict__ acc) {
  __shared__ float wred[4];
  const int t    = threadIdx.x;
  const int lane = t & 63;
  const int wv   = t >> 6;
  const int l15  = lane & 15;
  const int l4   = lane >> 4;            // 0..3
  const int g    = blockIdx.x * 4 + wv;  // pixel-group 0..2047
  const int b    = g >> 6;               // image
  const int hw0  = (g & 63) << 4;        // 16-pixel chunk

  // ---- A fragments (MFMA layout) + ||x||^2, straight from HBM ----------
  // lane (l15,l4): pixel hw0+l15, dims d = kk*32 + l4*8 + j
  const float* lx = latents + (((size_t)b * DIM) << 10) + hw0 + l15;
  v8bf a[8];
  float xn2 = 0.f;
  #pragma unroll
  for (int kk = 0; kk < 8; ++kk) {
    v8bf v;
    #pragma unroll
    for (int j = 0; j < 8; ++j) {
      const float f = lx[(size_t)(kk * 32 + l4 * 8 + j) << 10];
      xn2 = fmaf(f, f, xn2);
      v[j] = (__bf16)f;
    }
    a[kk] = v;
  }
  xn2 += __shfl_xor(xn2, 16, 64);
  xn2 += __shfl_xor(xn2, 32, 64);      // full ||x||^2 of pixel l15, all lanes

  // ---- argmin over 1024 codes, 16/tile, register-double-buffered -------
  // lane reads code row (ci*16+l15), bytes [kk*64 + l4*16, +16)
  const u16* ebase = Eb + l15 * DIM + l4 * 8;
  float minv[4];
  int   mini[4];
  #pragma unroll
  for (int i = 0; i < 4; ++i) { minv[i] = 3.4e38f; mini[i] = 0; }

  v8bf p0[8], p1[8];
  #pragma unroll
  for (int kk = 0; kk < 8; ++kk)
    p0[kk] = *(const v8bf*)(ebase + kk * 32);
  float nrm0 = norms[l15];

  for (int ci = 0; ci < 64; ci += 2) {
    #pragma unroll
    for (int kk = 0; kk < 8; ++kk)
      p1[kk] = *(const v8bf*)(ebase + (ci + 1) * 4096 + kk * 32);
    const float nrm1 = norms[(ci + 1) * 16 + l15];

    ARGMIN_STEP(p0, nrm0, ci * 16 + l15);

    if (ci + 2 < 64) {
      #pragma unroll
      for (int kk = 0; kk < 8; ++kk)
        p0[kk] = *(const v8bf*)(ebase + (ci + 2) * 4096 + kk * 32);
      nrm0 = norms[(ci + 2) * 16 + l15];
    }

    ARGMIN_STEP(p1, nrm1, (ci + 1) * 16 + l15);
  }

  // per-pixel argmin: butterfly across the 16 lanes sharing a pixel row
  #pragma unroll
  for (int i = 0; i < 4; ++i) {
    float v  = minv[i];
    int   ix = mini[i];
    #pragma unroll
    for (int m = 1; m < 16; m <<= 1) {
      const float ov = __shfl_xor(v, m, 64);
      const int   oi = __shfl_xor(ix, m, 64);
      if (ov < v || (ov == v && oi < ix)) { v = ov; ix = oi; }
    }
    minv[i] = v; mini[i] = ix;          // pixel l4*4+i, valid on all lanes
  }

  // ---- loss: sum over pixels of (minv + ||x||^2)  (= sum (q-x)^2) ------
  float xns[4];
  #pragma unroll
  for (int i = 0; i < 4; ++i) xns[i] = __shfl(xn2, l4 * 4 + i, 64);
  float lsum = (l15 == 0)
      ? (minv[0] + xns[0]) + (minv[1] + xns[1]) +
        (minv[2] + xns[2]) + (minv[3] + xns[3])
      : 0.f;
  #pragma unroll
  for (int m = 32; m; m >>= 1) lsum += __shfl_xor(lsum, m, 64);

  // ---- index for this lane's write pixel (hw0 + l15) --------------------
  const int src  = (l15 >> 2) << 4;     // lane holding pixels (l15>>2)*4+i
  const int idx0 = __shfl(mini[0], src, 64);
  const int idx1 = __shfl(mini[1], src, 64);
  const int idx2 = __shfl(mini[2], src, 64);
  const int idx3 = __shfl(mini[3], src, 64);
  const int idx  = (l15 & 2) ? ((l15 & 1) ? idx3 : idx2)
                             : ((l15 & 1) ? idx1 : idx0);

  // ---- gather E row, transposed coalesced write -------------------------
  const float* ep = E + ((size_t)idx << 8) + l4 * 8;
  float*       op = out + (((size_t)b * DIM) << 10) + hw0 + l15;
  #pragma unroll
  for (int kk = 0; kk < 8; ++kk) {
    const float4 e0 = *(const float4*)(ep + kk * 32);
    const float4 e1 = *(const float4*)(ep + kk * 32 + 4);
    const int d0 = kk * 32 + l4 * 8;
    op[(size_t)(d0 + 0) << 10] = e0.x;
    op[(size_t)(d0 + 1) << 10] = e0.y;
    op[(size_t)(d0 + 2) << 10] = e0.z;
    op[(size_t)(d0 + 3) << 10] = e0.w;
    op[(size_t)(d0 + 4) << 10] = e1.x;
    op[(size_t)(d0 + 5) << 10] = e1.y;
    op[(size_t)(d0 + 6) << 10] = e1.z;
    op[(size_t)(d0 + 7) << 10] = e1.w;
  }

  // ---- block loss reduction -> one atomic -------------------------------
  if (lane == 0) wred[wv] = lsum;
  __syncthreads();
  if (t == 0) atomicAdd(acc, wred[0] + wred[1] + wred[2] + wred[3]);
}

// ---------------------------------------------------------------- kernel D
__global__ void k_final(const float* __restrict__ acc, float* __restrict__ loss) {
  // vq_loss = (BETA + 1) * mean = 1.25 * sum / (N*D)
  *loss = *acc * (1.25f / 8388608.f);
}

// ----------------------------------------------------------------
extern "C" void kernel_launch(void* const* d_in, const int* in_sizes, int n_in,
                              void* d_out, int out_size, void* d_ws, size_t ws_size,
                              hipStream_t stream) {
  const float* latents = (const float*)d_in[0];
  const float* E       = (const float*)d_in[1];
  float* out = (float*)d_out;
  char*  ws  = (char*)d_ws;
  u16*   Eb    = (u16*)(ws + WS_EB);
  float* norms = (float*)(ws + WS_NORM);
  float* acc   = (float*)(ws + WS_ACC);

  k_prep<<<KCODE, 256, 0, stream>>>(E, Eb, norms, acc);
  k_vq<<<512, 256, 0, stream>>>(latents, Eb, E, norms, out, acc);
  k_final<<<1, 1, 0, stream>>>(acc, out + 8388608);
}